// Round 2
// baseline (313.434 us; speedup 1.0000x reference)
//
#include <hip/hip_runtime.h>

#define G_    32
#define N_    128
#define NP1_  129
#define H_    32
#define EAD_  16
#define MAXD_ 5
#define NE_   65536
#define NPTH_ 1048576

// ---------------------------------------------------------------------------
// Kernel 1: edge encoder into compact eaval[NE][H]; edge_map[(g,i,j)] = e+1.
// one thread per (edge, head); 32 consecutive threads write 128B contiguous.
// ---------------------------------------------------------------------------
__global__ __launch_bounds__(256) void edge_encode_kernel(
    const float* __restrict__ edge_attr,    // [NE][16]
    const int*   __restrict__ edge_index,   // [3][NE]
    const float* __restrict__ edge_enc_w,   // [H][16]
    float*       __restrict__ eaval,        // [NE][H]
    int*         __restrict__ edge_map) {   // [G][N][N], e+1 (0 = empty)
  int t = blockIdx.x * blockDim.x + threadIdx.x;
  if (t >= NE_ * H_) return;
  int e = t >> 5;
  int h = t & 31;
  const float* ea = edge_attr + e * EAD_;
  const float* w  = edge_enc_w + h * EAD_;
  float s = 0.f;
#pragma unroll
  for (int k = 0; k < EAD_; ++k) s += ea[k] * w[k];
  eaval[t] = s;
  if (h == 0) {
    int g = edge_index[e];
    int i = edge_index[NE_ + e];
    int j = edge_index[2 * NE_ + e];
    edge_map[(g * N_ + i) * N_ + j] = e + 1;
  }
}

// ---------------------------------------------------------------------------
// Kernel 2: compaction. 1 thread per path; keep paths whose source cell has
// an edge (the only ones with a nonzero contribution). ~12.5% survive.
// ---------------------------------------------------------------------------
__global__ __launch_bounds__(256) void compact_kernel(
    const int* __restrict__ path_index,     // [6][NPTH]
    const int* __restrict__ edge_map,       // [G][N][N]
    int*       __restrict__ wl_p,           // [NPTH]
    int*       __restrict__ wl_e,           // [NPTH]
    int*       __restrict__ counter) {
  int p = blockIdx.x * blockDim.x + threadIdx.x;
  if (p >= NPTH_) return;
  int pg = path_index[p];
  int ps = path_index[4 * NPTH_ + p];
  int pt = path_index[5 * NPTH_ + p];
  int m = edge_map[(pg * N_ + ps) * N_ + pt];   // random 4B in 2MB (L2)
  if (m) {
    int idx = atomicAdd(counter, 1);            // wave-aggregated by compiler
    wl_p[idx] = p;
    wl_e[idx] = m - 1;
  }
}

// ---------------------------------------------------------------------------
// Kernel 3: mixing over surviving paths. 32 lanes per path; lane k = head k.
// Grid-stride over the device-side worklist count.
// ---------------------------------------------------------------------------
__global__ __launch_bounds__(256) void mix_kernel(
    const int*   __restrict__ path_index,   // [6][NPTH]
    const float* __restrict__ eaval,        // [NE][H]
    const float* __restrict__ Wdis,         // edge_dis_emb flat [d][h][k]
    const int*   __restrict__ wl_p,
    const int*   __restrict__ wl_e,
    const int*   __restrict__ counter,
    float*       __restrict__ acc) {        // [G][N][N][H]
  int cnt = counter[0];
  int lane = threadIdx.x & 31;
  int grp  = threadIdx.x & 32;
  int slot = (blockIdx.x * blockDim.x + threadIdx.x) >> 5;
  int stride = (gridDim.x * blockDim.x) >> 5;
  for (int s = slot; s < cnt; s += stride) {
    int p = wl_p[s];                        // group-uniform -> broadcast
    int e = wl_e[s];
    int pg = path_index[p];
    int pi = path_index[NPTH_ + p];
    int pj = path_index[2 * NPTH_ + p];
    int pd = path_index[3 * NPTH_ + p];
    float rv = eaval[e * H_ + lane];        // 128B gather in 8MB (L2-warm)
    const float* Wd = Wdis + pd * H_ * H_;  // 20KB total, L1-resident
    float v = 0.f;
#pragma unroll
    for (int h = 0; h < H_; ++h) {
      float rh = __shfl(rv, grp + h, 64);
      v += rh * Wd[h * H_ + lane];
    }
    atomicAdd(&acc[(((pg * N_) + pi) * N_ + pj) * H_ + lane], v);
  }
}

// ---------------------------------------------------------------------------
// Kernel 4: final assembly. One block per (g, a) output row.
// out[g][h][a][b] = 2*attn_bias[g][a][b]
//   + (a==0 || b==0) ? virt[h]
//   : spe[spatial_pos[g][a-1][b-1]][h] + acc[g][a-1][b-1][h] / sp_norm
// ---------------------------------------------------------------------------
__global__ __launch_bounds__(256) void output_kernel(
    const float* __restrict__ attn_bias,    // [G][129][129]
    const int*   __restrict__ spatial_pos,  // [G][N][N]
    const float* __restrict__ spe,          // [512][H]
    const float* __restrict__ virt,         // [H]
    const float* __restrict__ acc,          // [G][N][N][H]
    float*       __restrict__ out) {        // [G][H][129][129]
  __shared__ float lds_acc[N_ * 33];        // padded: conflict-free transpose
  __shared__ float lds_inv[N_];
  __shared__ int   lds_sp[N_];
  __shared__ float lds_virt[H_];

  int blk = blockIdx.x;
  int g = blk / NP1_;
  int a = blk - g * NP1_;
  int tid = threadIdx.x;

  if (tid < H_) lds_virt[tid] = virt[tid];

  const float* ab = attn_bias + (g * NP1_ + a) * NP1_;

  if (a == 0) {
    __syncthreads();
    for (int t = tid; t < H_ * NP1_; t += 256) {
      int h = t / NP1_;
      int b = t - h * NP1_;
      out[((g * H_ + h) * NP1_) * NP1_ + b] = 2.f * ab[b] + lds_virt[h];
    }
    return;
  }

  int i = a - 1;
  const float* acc_row = acc + ((g * N_ + i) * N_) * H_;
  for (int t = tid; t < N_ * H_; t += 256) {
    int j = t >> 5;
    int h = t & 31;
    lds_acc[j * 33 + h] = acc_row[t];
  }
  if (tid < N_) {
    int s = spatial_pos[(g * N_ + i) * N_ + tid];
    lds_sp[tid] = s;
    int s2 = (s == 0) ? 1 : s;
    s2 = (s2 > 1) ? s2 - 1 : s2;
    s2 = (s2 > MAXD_) ? MAXD_ : s2;
    lds_inv[tid] = 1.0f / (float)s2;
  }
  __syncthreads();

  for (int t = tid; t < H_ * NP1_; t += 256) {
    int h = t / NP1_;
    int b = t - h * NP1_;
    float val = 2.f * ab[b];
    if (b == 0) {
      val += lds_virt[h];
    } else {
      int j = b - 1;
      val += spe[lds_sp[j] * H_ + h] + lds_acc[j * 33 + h] * lds_inv[j];
    }
    out[((g * H_ + h) * NP1_ + a) * NP1_ + b] = val;
  }
}

// ---------------------------------------------------------------------------
extern "C" void kernel_launch(void* const* d_in, const int* in_sizes, int n_in,
                              void* d_out, int out_size, void* d_ws, size_t ws_size,
                              hipStream_t stream) {
  const float* attn_bias   = (const float*)d_in[0];
  const int*   spatial_pos = (const int*)d_in[1];
  const int*   edge_index  = (const int*)d_in[2];
  const float* edge_attr   = (const float*)d_in[3];
  const int*   path_index  = (const int*)d_in[4];
  const float* edge_enc_w  = (const float*)d_in[5];
  const float* spe         = (const float*)d_in[6];
  const float* virt        = (const float*)d_in[7];
  const float* edge_dis    = (const float*)d_in[8];
  float* out = (float*)d_out;

  const size_t ACC_ELEMS = (size_t)G_ * N_ * N_ * H_;   // 16.7M floats, 64MB
  const size_t MAP_ELEMS = (size_t)G_ * N_ * N_;        // 512K ints, 2MB

  float* acc      = (float*)d_ws;
  int*   edge_map = (int*)(acc + ACC_ELEMS);
  float* eaval    = (float*)(edge_map + MAP_ELEMS);
  int*   wl_p     = (int*)(eaval + (size_t)NE_ * H_);
  int*   wl_e     = wl_p + NPTH_;
  int*   counter  = wl_e + NPTH_;

  // zero acc + edge_map (contiguous, 66MB) and the worklist counter
  hipMemsetAsync(acc, 0, (ACC_ELEMS + MAP_ELEMS) * sizeof(float), stream);
  hipMemsetAsync(counter, 0, sizeof(int), stream);

  // edge encoder + map
  {
    int total = NE_ * H_;
    edge_encode_kernel<<<(total + 255) / 256, 256, 0, stream>>>(
        edge_attr, edge_index, edge_enc_w, eaval, edge_map);
  }
  // path compaction
  compact_kernel<<<(NPTH_ + 255) / 256, 256, 0, stream>>>(
      path_index, edge_map, wl_p, wl_e, counter);
  // mixing over survivors
  mix_kernel<<<2048, 256, 0, stream>>>(
      path_index, eaval, edge_dis, wl_p, wl_e, counter, acc);
  // final output
  output_kernel<<<G_ * NP1_, 256, 0, stream>>>(
      attn_bias, spatial_pos, spe, virt, acc, out);
}

// Round 3
// 133.702 us; speedup vs baseline: 2.3443x; 2.3443x over previous
//
#include <hip/hip_runtime.h>

#define G_    32
#define N_    128
#define NP1_  129
#define H_    32
#define EAD_  16
#define MAXD_ 5
#define NE_   65536
#define NPTH_ 1048576
#define PPB_  1024   // paths per block in the fused path kernel

// ---------------------------------------------------------------------------
// Kernel 1: edge encoder into compact eaval[NE][H]; edge_map[(g,i,j)] = e+1.
// one thread per (edge, head); 32 consecutive threads write 128B contiguous.
// ---------------------------------------------------------------------------
__global__ __launch_bounds__(256) void edge_encode_kernel(
    const float* __restrict__ edge_attr,    // [NE][16]
    const int*   __restrict__ edge_index,   // [3][NE]
    const float* __restrict__ edge_enc_w,   // [H][16]
    float*       __restrict__ eaval,        // [NE][H]
    int*         __restrict__ edge_map) {   // [G][N][N], e+1 (0 = empty)
  int t = blockIdx.x * blockDim.x + threadIdx.x;
  if (t >= NE_ * H_) return;
  int e = t >> 5;
  int h = t & 31;
  const float* ea = edge_attr + e * EAD_;
  const float* w  = edge_enc_w + h * EAD_;
  float s = 0.f;
#pragma unroll
  for (int k = 0; k < EAD_; ++k) s += ea[k] * w[k];
  eaval[t] = s;
  if (h == 0) {
    int g = edge_index[e];
    int i = edge_index[NE_ + e];
    int j = edge_index[2 * NE_ + e];
    edge_map[(g * N_ + i) * N_ + j] = e + 1;
  }
}

// ---------------------------------------------------------------------------
// Kernel 2 (fused): block-local compaction + mixing.
// Phase 1: 256 threads check 1024 paths against edge_map (2MB, L2);
//          survivors (~12.5%) pushed to an LDS queue (LDS atomics, cheap).
// Phase 2: the block's 8 lane-groups drain the queue: gather eaval row,
//          shfl-broadcast x Wdis mix, atomicAdd into acc (uncontended).
// ---------------------------------------------------------------------------
__global__ __launch_bounds__(256) void path_fused_kernel(
    const int*   __restrict__ path_index,   // [6][NPTH]
    const int*   __restrict__ edge_map,     // [G][N][N]
    const float* __restrict__ eaval,        // [NE][H]
    const float* __restrict__ Wdis,         // edge_dis_emb flat [d][h][k]
    float*       __restrict__ acc) {        // [G][N][N][H]
  __shared__ int q_p[PPB_];
  __shared__ int q_e[PPB_];
  __shared__ int q_cnt;
  int tid = threadIdx.x;
  if (tid == 0) q_cnt = 0;
  __syncthreads();

  int base = blockIdx.x * PPB_;
  // phase 1: check 4 paths per thread (independent loads -> pipelined)
#pragma unroll
  for (int k = 0; k < PPB_; k += 256) {
    int p = base + k + tid;
    int pg = path_index[p];
    int ps = path_index[4 * NPTH_ + p];
    int pt = path_index[5 * NPTH_ + p];
    int m = edge_map[(pg * N_ + ps) * N_ + pt];   // random 4B in 2MB (L2)
    if (m) {
      int idx = atomicAdd(&q_cnt, 1);             // LDS atomic
      q_p[idx] = p;
      q_e[idx] = m - 1;
    }
  }
  __syncthreads();
  int cnt = q_cnt;

  // phase 2: 8 groups of 32 lanes drain the queue
  int lane = tid & 31;
  int grp  = tid & 32;                            // shfl base within wave64
  for (int s = tid >> 5; s < cnt; s += 8) {
    int p = q_p[s];                               // LDS broadcast
    int e = q_e[s];
    int pg = path_index[p];                       // scattered, ~L2 (4KB window)
    int pi = path_index[NPTH_ + p];
    int pj = path_index[2 * NPTH_ + p];
    int pd = path_index[3 * NPTH_ + p];
    float rv = eaval[e * H_ + lane];              // 128B gather in 8MB
    const float* Wd = Wdis + pd * H_ * H_;        // 20KB total, L1-resident
    float v = 0.f;
#pragma unroll
    for (int h = 0; h < H_; ++h) {
      float rh = __shfl(rv, grp + h, 64);
      v += rh * Wd[h * H_ + lane];
    }
    atomicAdd(&acc[(((pg * N_) + pi) * N_ + pj) * H_ + lane], v);
  }
}

// ---------------------------------------------------------------------------
// Kernel 3: final assembly. One block per (g, a) output row.
// out[g][h][a][b] = 2*attn_bias[g][a][b]
//   + (a==0 || b==0) ? virt[h]
//   : spe[spatial_pos[g][a-1][b-1]][h] + acc[g][a-1][b-1][h] / sp_norm
// ---------------------------------------------------------------------------
__global__ __launch_bounds__(256) void output_kernel(
    const float* __restrict__ attn_bias,    // [G][129][129]
    const int*   __restrict__ spatial_pos,  // [G][N][N]
    const float* __restrict__ spe,          // [512][H]
    const float* __restrict__ virt,         // [H]
    const float* __restrict__ acc,          // [G][N][N][H]
    float*       __restrict__ out) {        // [G][H][129][129]
  __shared__ float lds_acc[N_ * 33];        // padded: conflict-free transpose
  __shared__ float lds_inv[N_];
  __shared__ int   lds_sp[N_];
  __shared__ float lds_virt[H_];

  int blk = blockIdx.x;
  int g = blk / NP1_;
  int a = blk - g * NP1_;
  int tid = threadIdx.x;

  if (tid < H_) lds_virt[tid] = virt[tid];

  const float* ab = attn_bias + (g * NP1_ + a) * NP1_;

  if (a == 0) {
    __syncthreads();
    for (int t = tid; t < H_ * NP1_; t += 256) {
      int h = t / NP1_;
      int b = t - h * NP1_;
      out[((g * H_ + h) * NP1_) * NP1_ + b] = 2.f * ab[b] + lds_virt[h];
    }
    return;
  }

  int i = a - 1;
  const float* acc_row = acc + ((g * N_ + i) * N_) * H_;
  for (int t = tid; t < N_ * H_; t += 256) {
    int j = t >> 5;
    int h = t & 31;
    lds_acc[j * 33 + h] = acc_row[t];
  }
  if (tid < N_) {
    int s = spatial_pos[(g * N_ + i) * N_ + tid];
    lds_sp[tid] = s;
    int s2 = (s == 0) ? 1 : s;
    s2 = (s2 > 1) ? s2 - 1 : s2;
    s2 = (s2 > MAXD_) ? MAXD_ : s2;
    lds_inv[tid] = 1.0f / (float)s2;
  }
  __syncthreads();

  for (int t = tid; t < H_ * NP1_; t += 256) {
    int h = t / NP1_;
    int b = t - h * NP1_;
    float val = 2.f * ab[b];
    if (b == 0) {
      val += lds_virt[h];
    } else {
      int j = b - 1;
      val += spe[lds_sp[j] * H_ + h] + lds_acc[j * 33 + h] * lds_inv[j];
    }
    out[((g * H_ + h) * NP1_ + a) * NP1_ + b] = val;
  }
}

// ---------------------------------------------------------------------------
extern "C" void kernel_launch(void* const* d_in, const int* in_sizes, int n_in,
                              void* d_out, int out_size, void* d_ws, size_t ws_size,
                              hipStream_t stream) {
  const float* attn_bias   = (const float*)d_in[0];
  const int*   spatial_pos = (const int*)d_in[1];
  const int*   edge_index  = (const int*)d_in[2];
  const float* edge_attr   = (const float*)d_in[3];
  const int*   path_index  = (const int*)d_in[4];
  const float* edge_enc_w  = (const float*)d_in[5];
  const float* spe         = (const float*)d_in[6];
  const float* virt        = (const float*)d_in[7];
  const float* edge_dis    = (const float*)d_in[8];
  float* out = (float*)d_out;

  const size_t ACC_ELEMS = (size_t)G_ * N_ * N_ * H_;   // 16.7M floats, 64MB
  const size_t MAP_ELEMS = (size_t)G_ * N_ * N_;        // 512K ints, 2MB

  float* acc      = (float*)d_ws;
  int*   edge_map = (int*)(acc + ACC_ELEMS);
  float* eaval    = (float*)(edge_map + MAP_ELEMS);

  // zero acc + edge_map (contiguous, 66MB)
  hipMemsetAsync(acc, 0, (ACC_ELEMS + MAP_ELEMS) * sizeof(float), stream);

  // edge encoder + map
  {
    int total = NE_ * H_;
    edge_encode_kernel<<<(total + 255) / 256, 256, 0, stream>>>(
        edge_attr, edge_index, edge_enc_w, eaval, edge_map);
  }
  // fused compaction + mixing
  path_fused_kernel<<<NPTH_ / PPB_, 256, 0, stream>>>(
      path_index, edge_map, eaval, edge_dis, acc);
  // final output
  output_kernel<<<G_ * NP1_, 256, 0, stream>>>(
      attn_bias, spatial_pos, spe, virt, acc, out);
}

// Round 4
// 105.818 us; speedup vs baseline: 2.9620x; 1.2635x over previous
//
#include <hip/hip_runtime.h>

#define G_    32
#define N_    128
#define NP1_  129
#define H_    32
#define EAD_  16
#define MAXD_ 5
#define NE_   65536
#define NPTH_ 1048576
#define PPB_  1024   // paths per block in the fused path kernel

// ---------------------------------------------------------------------------
// Kernel 1: edge encoder into compact eaval[NE][H]; edge_map[(g,i,j)] = e+1.
// one thread per (edge, head); 32 consecutive threads write 128B contiguous.
// ---------------------------------------------------------------------------
__global__ __launch_bounds__(256) void edge_encode_kernel(
    const float* __restrict__ edge_attr,    // [NE][16]
    const int*   __restrict__ edge_index,   // [3][NE]
    const float* __restrict__ edge_enc_w,   // [H][16]
    float*       __restrict__ eaval,        // [NE][H]
    int*         __restrict__ edge_map) {   // [G][N][N], e+1 (0 = empty)
  int t = blockIdx.x * blockDim.x + threadIdx.x;
  if (t >= NE_ * H_) return;
  int e = t >> 5;
  int h = t & 31;
  const float* ea = edge_attr + e * EAD_;
  const float* w  = edge_enc_w + h * EAD_;
  float s = 0.f;
#pragma unroll
  for (int k = 0; k < EAD_; ++k) s += ea[k] * w[k];
  eaval[t] = s;
  if (h == 0) {
    int g = edge_index[e];
    int i = edge_index[NE_ + e];
    int j = edge_index[2 * NE_ + e];
    edge_map[(g * N_ + i) * N_ + j] = e + 1;
  }
}

// ---------------------------------------------------------------------------
// Kernel 2 (fused): block-local compaction + mixing.
// Phase 1: 256 threads check 1024 paths against edge_map (2MB, L2);
//          survivors (~12.5%) pushed to an LDS queue (LDS atomics, cheap).
// Phase 2: the block's 8 lane-groups drain the queue: gather eaval row,
//          shfl-broadcast x Wdis mix, atomicAdd into acc (uncontended).
// ---------------------------------------------------------------------------
__global__ __launch_bounds__(256) void path_fused_kernel(
    const int*   __restrict__ path_index,   // [6][NPTH]
    const int*   __restrict__ edge_map,     // [G][N][N]
    const float* __restrict__ eaval,        // [NE][H]
    const float* __restrict__ Wdis,         // edge_dis_emb flat [d][h][k]
    float*       __restrict__ acc) {        // [G][N][N][H]
  __shared__ int q_p[PPB_];
  __shared__ int q_e[PPB_];
  __shared__ int q_cnt;
  int tid = threadIdx.x;
  if (tid == 0) q_cnt = 0;
  __syncthreads();

  int base = blockIdx.x * PPB_;
  // phase 1: check 4 paths per thread (independent loads -> pipelined)
#pragma unroll
  for (int k = 0; k < PPB_; k += 256) {
    int p = base + k + tid;
    int pg = path_index[p];
    int ps = path_index[4 * NPTH_ + p];
    int pt = path_index[5 * NPTH_ + p];
    int m = edge_map[(pg * N_ + ps) * N_ + pt];   // random 4B in 2MB (L2)
    if (m) {
      int idx = atomicAdd(&q_cnt, 1);             // LDS atomic
      q_p[idx] = p;
      q_e[idx] = m - 1;
    }
  }
  __syncthreads();
  int cnt = q_cnt;

  // phase 2: 8 groups of 32 lanes drain the queue
  int lane = tid & 31;
  int grp  = tid & 32;                            // shfl base within wave64
  for (int s = tid >> 5; s < cnt; s += 8) {
    int p = q_p[s];                               // LDS broadcast
    int e = q_e[s];
    int pg = path_index[p];                       // scattered, ~L2 (4KB window)
    int pi = path_index[NPTH_ + p];
    int pj = path_index[2 * NPTH_ + p];
    int pd = path_index[3 * NPTH_ + p];
    float rv = eaval[e * H_ + lane];              // 128B gather in 8MB
    const float* Wd = Wdis + pd * H_ * H_;        // 20KB total, L1-resident
    float v = 0.f;
#pragma unroll
    for (int h = 0; h < H_; ++h) {
      float rh = __shfl(rv, grp + h, 64);
      v += rh * Wd[h * H_ + lane];
    }
    atomicAdd(&acc[(((pg * N_) + pi) * N_ + pj) * H_ + lane], v);
  }
}

// ---------------------------------------------------------------------------
// Kernel 3: final assembly. One block per (g, a) output row.
// Phase A (h fast-varying): stage val[j][h] = spe[sp[j]][h] + acc[j][h]*inv(j)
//   into padded LDS — spe rows read as contiguous 128B per lane-group.
// Phase B: write out[g][h][a][:] reading LDS transposed (stride 33, no
//   bank conflicts); no global gathers in the write loop.
// ---------------------------------------------------------------------------
__global__ __launch_bounds__(256) void output_kernel(
    const float* __restrict__ attn_bias,    // [G][129][129]
    const int*   __restrict__ spatial_pos,  // [G][N][N]
    const float* __restrict__ spe,          // [512][H]
    const float* __restrict__ virt,         // [H]
    const float* __restrict__ acc,          // [G][N][N][H]
    float*       __restrict__ out) {        // [G][H][129][129]
  __shared__ float lds_val[N_ * 33];        // padded: conflict-free transpose
  __shared__ float lds_virt[H_];

  int blk = blockIdx.x;
  int g = blk / NP1_;
  int a = blk - g * NP1_;
  int tid = threadIdx.x;

  if (tid < H_) lds_virt[tid] = virt[tid];

  const float* ab = attn_bias + (g * NP1_ + a) * NP1_;

  if (a == 0) {
    __syncthreads();
    for (int t = tid; t < H_ * NP1_; t += 256) {
      int h = t / NP1_;
      int b = t - h * NP1_;
      out[((g * H_ + h) * NP1_) * NP1_ + b] = 2.f * ab[b] + lds_virt[h];
    }
    return;
  }

  int i = a - 1;
  const float* acc_row = acc + ((g * N_ + i) * N_) * H_;
  const int*   sp_row  = spatial_pos + (g * N_ + i) * N_;

  // phase A: j = t>>5 (group-uniform), h = t&31 (lane) -> coalesced spe/acc
  for (int t = tid; t < N_ * H_; t += 256) {
    int j = t >> 5;
    int h = t & 31;
    int s = sp_row[j];                      // broadcast within lane-group
    int s2 = (s == 0) ? 1 : s;
    s2 = (s2 > 1) ? s2 - 1 : s2;
    s2 = (s2 > MAXD_) ? MAXD_ : s2;
    float inv = 1.0f / (float)s2;
    lds_val[j * 33 + h] = spe[s * H_ + h] + acc_row[t] * inv;
  }
  __syncthreads();

  // phase B: pure write loop; LDS transposed reads, conflict-free
  for (int t = tid; t < H_ * NP1_; t += 256) {
    int h = t / NP1_;
    int b = t - h * NP1_;
    float val = 2.f * ab[b];
    if (b == 0) {
      val += lds_virt[h];
    } else {
      val += lds_val[(b - 1) * 33 + h];
    }
    out[((g * H_ + h) * NP1_ + a) * NP1_ + b] = val;
  }
}

// ---------------------------------------------------------------------------
extern "C" void kernel_launch(void* const* d_in, const int* in_sizes, int n_in,
                              void* d_out, int out_size, void* d_ws, size_t ws_size,
                              hipStream_t stream) {
  const float* attn_bias   = (const float*)d_in[0];
  const int*   spatial_pos = (const int*)d_in[1];
  const int*   edge_index  = (const int*)d_in[2];
  const float* edge_attr   = (const float*)d_in[3];
  const int*   path_index  = (const int*)d_in[4];
  const float* edge_enc_w  = (const float*)d_in[5];
  const float* spe         = (const float*)d_in[6];
  const float* virt        = (const float*)d_in[7];
  const float* edge_dis    = (const float*)d_in[8];
  float* out = (float*)d_out;

  const size_t ACC_ELEMS = (size_t)G_ * N_ * N_ * H_;   // 16.7M floats, 64MB
  const size_t MAP_ELEMS = (size_t)G_ * N_ * N_;        // 512K ints, 2MB

  float* acc      = (float*)d_ws;
  int*   edge_map = (int*)(acc + ACC_ELEMS);
  float* eaval    = (float*)(edge_map + MAP_ELEMS);

  // zero acc + edge_map (contiguous, 66MB)
  hipMemsetAsync(acc, 0, (ACC_ELEMS + MAP_ELEMS) * sizeof(float), stream);

  // edge encoder + map
  {
    int total = NE_ * H_;
    edge_encode_kernel<<<(total + 255) / 256, 256, 0, stream>>>(
        edge_attr, edge_index, edge_enc_w, eaval, edge_map);
  }
  // fused compaction + mixing
  path_fused_kernel<<<NPTH_ / PPB_, 256, 0, stream>>>(
      path_index, edge_map, eaval, edge_dis, acc);
  // final output
  output_kernel<<<G_ * NP1_, 256, 0, stream>>>(
      attn_bias, spatial_pos, spe, virt, acc, out);
}